// Round 3
// baseline (753.339 us; speedup 1.0000x reference)
//
#include <hip/hip_runtime.h>
#include <hip/hip_bf16.h>
#include <cstdint>
#include <cstddef>

#define B_ 64
#define S_ 2048
#define H_ 512

typedef __bf16 bf16x8 __attribute__((ext_vector_type(8)));
typedef float  f32x4  __attribute__((ext_vector_type(4)));

__device__ __forceinline__ float fast_tanh(float x) {
    float e = __expf(2.0f * x);
    return 1.0f - __fdividef(2.0f, e + 1.0f);
}

// ---------------------------------------------------------------------------
// W1 [k][n] f32  ->  Wt [n][k] bf16   (transpose + downcast, LDS-tiled)
// ---------------------------------------------------------------------------
__global__ __launch_bounds__(256) void w1t_kernel(const float* __restrict__ W1,
                                                  unsigned short* __restrict__ Wt) {
    __shared__ float tile[32][33];
    int tn = blockIdx.x >> 4;   // n-tile  (16)
    int tk = blockIdx.x & 15;   // k-tile  (16)
    int lx = threadIdx.x & 31;
    int ly = threadIdx.x >> 5;  // 0..7
#pragma unroll
    for (int i = 0; i < 4; ++i) {
        int k = tk * 32 + ly + i * 8;
        tile[ly + i * 8][lx] = W1[k * H_ + tn * 32 + lx];   // coalesced read
    }
    __syncthreads();
#pragma unroll
    for (int i = 0; i < 4; ++i) {
        int n = tn * 32 + ly + i * 8;
        float v = tile[lx][ly + i * 8];                      // W1[tk*32+lx][n]
        __bf16 bv = (__bf16)v;
        Wt[(size_t)n * H_ + tk * 32 + lx] = *(unsigned short*)&bv;  // coalesced write
    }
}

// ---------------------------------------------------------------------------
// cvals[b][h] = b1[h] + b2[h] + sum_k hidden[b][k] * W2[k][h]
// ---------------------------------------------------------------------------
__global__ __launch_bounds__(512) void hidproj_kernel(const float* __restrict__ hidden,
                                                      const float* __restrict__ W2,
                                                      const float* __restrict__ b1,
                                                      const float* __restrict__ b2,
                                                      float* __restrict__ cvals) {
    int b = blockIdx.x;
    int h = threadIdx.x;
    float acc = b1[h] + b2[h];
    const float* hp = hidden + b * H_;
    const float* wp = W2 + h;
#pragma unroll 8
    for (int k = 0; k < H_; ++k) acc = fmaf(hp[k], wp[(size_t)k * H_], acc);
    cvals[b * H_ + h] = acc;
}

// ---------------------------------------------------------------------------
// Fused: logits[b][s] += sum_{h in ntile} V[h] * tanh((enc@W1)[b,s,h] + cvals[b,h])
// 128x128 tile, 4 waves, bf16 MFMA 16x16x32.
// NO LDS, NO barriers: A (enc f32) per-lane direct-to-reg + in-reg bf16 cvt;
// B (Wt bf16, 512 KB, L2-resident) per-lane direct-to-reg.
// Manual 1-deep ping-pong pipeline, fully unrolled (static reg indices).
// ---------------------------------------------------------------------------
__global__ __launch_bounds__(256) void score_kernel(const float* __restrict__ enc,
                                                    const unsigned short* __restrict__ Wt,
                                                    const float* __restrict__ cvals,
                                                    const float* __restrict__ Vp,
                                                    float* __restrict__ logits) {
    // XCD-bijective swizzle: 4096 % 8 == 0
    int orig = blockIdx.x;
    int wg   = (orig & 7) * 512 + (orig >> 3);
    int b     = wg >> 6;
    int stile = (wg >> 2) & 15;
    int ntile = wg & 3;

    int tid  = threadIdx.x;
    int wid  = tid >> 6;
    int lane = tid & 63;
    int wm = wid >> 1, wn = wid & 1;
    int rsel = lane & 15;        // fragment row/col within 16
    int g    = lane >> 4;        // k-group 0..3

    f32x4 acc[4][4];
#pragma unroll
    for (int m = 0; m < 4; ++m)
#pragma unroll
        for (int n = 0; n < 4; ++n) acc[m][n] = (f32x4){0.f, 0.f, 0.f, 0.f};

    // Per-lane row pointers (k-base folded in): A rows for this lane's 4 m-frags,
    // B rows for this lane's 4 n-frags. Per half-step s (32 k), offset = s*32 elems.
    const float* Arow[4];
#pragma unroll
    for (int m = 0; m < 4; ++m)
        Arow[m] = enc + ((size_t)(b * S_ + stile * 128 + wm * 64 + m * 16 + rsel)) * H_ + g * 8;
    const unsigned short* Brow[4];
#pragma unroll
    for (int n = 0; n < 4; ++n)
        Brow[n] = Wt + ((size_t)(ntile * 128 + wn * 64 + n * 16 + rsel)) * H_ + g * 8;

    float4 rA[2][4][2];   // [buf][m][half-of-8-floats]
    bf16x8 rB[2][4];      // [buf][n]

    // prologue: issue half-step 0
#pragma unroll
    for (int m = 0; m < 4; ++m) {
        rA[0][m][0] = *(const float4*)(Arow[m]);
        rA[0][m][1] = *(const float4*)(Arow[m] + 4);
    }
#pragma unroll
    for (int n = 0; n < 4; ++n)
        rB[0][n] = *(const bf16x8*)(Brow[n]);

#pragma unroll
    for (int s = 0; s < 16; ++s) {          // 16 half-steps of K=32
        const int cur = s & 1;
        if (s < 15) {
            const int nxt = cur ^ 1;
            const int so  = (s + 1) * 32;
#pragma unroll
            for (int m = 0; m < 4; ++m) {
                rA[nxt][m][0] = *(const float4*)(Arow[m] + so);
                rA[nxt][m][1] = *(const float4*)(Arow[m] + so + 4);
            }
#pragma unroll
            for (int n = 0; n < 4; ++n)
                rB[nxt][n] = *(const bf16x8*)(Brow[n] + so);
        }
        bf16x8 af[4];
#pragma unroll
        for (int m = 0; m < 4; ++m) {
            const float* f = (const float*)&rA[cur][m][0];
#pragma unroll
            for (int j = 0; j < 8; ++j) af[m][j] = (__bf16)f[j];
        }
#pragma unroll
        for (int m = 0; m < 4; ++m)
#pragma unroll
            for (int n = 0; n < 4; ++n)
                acc[m][n] = __builtin_amdgcn_mfma_f32_16x16x32_bf16(
                    af[m], rB[cur][n], acc[m][n], 0, 0, 0);
    }

    // epilogue: tanh + V-dot + row reduce + atomic partial logits
    int csel = lane & 15;
    float cw[4], vv[4];
#pragma unroll
    for (int n = 0; n < 4; ++n) {
        int col = ntile * 128 + wn * 64 + n * 16 + csel;
        cw[n] = cvals[b * H_ + col];
        vv[n] = Vp[col];
    }
    float part[16];
#pragma unroll
    for (int m = 0; m < 4; ++m)
#pragma unroll
        for (int r = 0; r < 4; ++r) {
            float p = 0.f;
#pragma unroll
            for (int n = 0; n < 4; ++n) {
                float s = fast_tanh(acc[m][n][r] + cw[n]);
                p = fmaf(vv[n], s, p);
            }
            part[m * 4 + r] = p;
        }
#pragma unroll
    for (int i = 0; i < 16; ++i)
#pragma unroll
        for (int off = 1; off < 16; off <<= 1)
            part[i] += __shfl_xor(part[i], off);

    if (csel == 0) {
        int gq = lane >> 4;
#pragma unroll
        for (int m = 0; m < 4; ++m)
#pragma unroll
            for (int r = 0; r < 4; ++r) {
                int row = stile * 128 + wm * 64 + m * 16 + gq * 4 + r;
                atomicAdd(&logits[b * S_ + row], part[m * 4 + r]);
            }
    }
}

// ---------------------------------------------------------------------------
// softmax over s per b
// ---------------------------------------------------------------------------
__global__ __launch_bounds__(256) void softmax_kernel(const float* __restrict__ logits,
                                                      float* __restrict__ wout) {
    int b = blockIdx.x;
    int t = threadIdx.x;
    __shared__ float red[8];
    float v[8];
#pragma unroll
    for (int i = 0; i < 8; ++i) v[i] = logits[b * S_ + t + i * 256];
    float m = v[0];
#pragma unroll
    for (int i = 1; i < 8; ++i) m = fmaxf(m, v[i]);
#pragma unroll
    for (int off = 32; off >= 1; off >>= 1) m = fmaxf(m, __shfl_xor(m, off));
    int wid = t >> 6, lane = t & 63;
    if (lane == 0) red[wid] = m;
    __syncthreads();
    m = fmaxf(fmaxf(red[0], red[1]), fmaxf(red[2], red[3]));
    float s = 0.f;
#pragma unroll
    for (int i = 0; i < 8; ++i) { v[i] = __expf(v[i] - m); s += v[i]; }
#pragma unroll
    for (int off = 32; off >= 1; off >>= 1) s += __shfl_xor(s, off);
    if (lane == 0) red[4 + wid] = s;
    __syncthreads();
    float tot = red[4] + red[5] + red[6] + red[7];
    float inv = __fdividef(1.0f, tot);
#pragma unroll
    for (int i = 0; i < 8; ++i) wout[b * S_ + t + i * 256] = v[i] * inv;
}

// ---------------------------------------------------------------------------
// context[b][h] = sum_s w[b][s] * enc[b][s][h]
// ---------------------------------------------------------------------------
__global__ __launch_bounds__(512) void context_kernel(const float* __restrict__ enc,
                                                      const float* __restrict__ w,
                                                      float* __restrict__ ctx) {
    int b  = blockIdx.x >> 4;
    int sc = blockIdx.x & 15;
    int h  = threadIdx.x;
    const float* ep = enc + ((size_t)(b * S_ + sc * 128)) * H_ + h;
    const float* wp = w + b * S_ + sc * 128;
    float acc = 0.f;
#pragma unroll 4
    for (int i = 0; i < 128; ++i) acc = fmaf(wp[i], ep[(size_t)i * H_], acc);
    atomicAdd(&ctx[b * H_ + h], acc);
}

// ---------------------------------------------------------------------------
extern "C" void kernel_launch(void* const* d_in, const int* in_sizes, int n_in,
                              void* d_out, int out_size, void* d_ws, size_t ws_size,
                              hipStream_t stream) {
    (void)in_sizes; (void)n_in; (void)out_size; (void)ws_size;
    const float* enc    = (const float*)d_in[0];
    const float* hidden = (const float*)d_in[1];
    const float* W1     = (const float*)d_in[2];
    const float* b1     = (const float*)d_in[3];
    const float* W2     = (const float*)d_in[4];
    const float* b2     = (const float*)d_in[5];
    const float* Vp     = (const float*)d_in[6];
    // d_in[7] (bV) unused: softmax is shift-invariant and logits are not an output.

    char* ws = (char*)d_ws;
    unsigned short* Wt = (unsigned short*)ws;                    // 512 KB
    float* cvals  = (float*)(ws + 524288);                       // 128 KB
    float* logits = (float*)(ws + 524288 + 131072);              // 512 KB

    float* ctx  = (float*)d_out;          // [64,512]
    float* wout = ctx + B_ * H_;          // [64,2048,1]

    hipMemsetAsync(logits, 0, (size_t)B_ * S_ * sizeof(float), stream);
    hipMemsetAsync(ctx,    0, (size_t)B_ * H_ * sizeof(float), stream);

    w1t_kernel<<<256, 256, 0, stream>>>(W1, Wt);
    hidproj_kernel<<<64, 512, 0, stream>>>(hidden, W2, b1, b2, cvals);
    score_kernel<<<4096, 256, 0, stream>>>(enc, Wt, cvals, Vp, logits);
    softmax_kernel<<<64, 256, 0, stream>>>(logits, wout);
    context_kernel<<<1024, 512, 0, stream>>>(enc, wout, ctx);
}

// Round 7
// 551.522 us; speedup vs baseline: 1.3659x; 1.3659x over previous
//
#include <hip/hip_runtime.h>
#include <hip/hip_bf16.h>
#include <cstdint>
#include <cstddef>

#define B_ 64
#define S_ 2048
#define H_ 512

typedef __bf16 bf16x8 __attribute__((ext_vector_type(8)));
typedef float  f32x4  __attribute__((ext_vector_type(4)));

__device__ __forceinline__ float fast_tanh(float x) {
    float e = __expf(2.0f * x);
    return 1.0f - __fdividef(2.0f, e + 1.0f);
}

// ---------------------------------------------------------------------------
// prep: blocks 0..255  : W1 [k][n] f32 -> Wt [n][k] bf16 (transpose+downcast)
//       blocks 256..383: cvals[b][h] = b1[h]+b2[h]+ hidden[b,:]·W2[:,h]
// ---------------------------------------------------------------------------
__global__ __launch_bounds__(256) void prep_kernel(const float* __restrict__ W1,
                                                   unsigned short* __restrict__ Wt,
                                                   const float* __restrict__ hidden,
                                                   const float* __restrict__ W2,
                                                   const float* __restrict__ b1,
                                                   const float* __restrict__ b2,
                                                   float* __restrict__ cvals) {
    if (blockIdx.x < 256) {
        __shared__ float tile[32][33];
        int tn = blockIdx.x >> 4;
        int tk = blockIdx.x & 15;
        int lx = threadIdx.x & 31;
        int ly = threadIdx.x >> 5;
#pragma unroll
        for (int i = 0; i < 4; ++i) {
            int k = tk * 32 + ly + i * 8;
            tile[ly + i * 8][lx] = W1[k * H_ + tn * 32 + lx];
        }
        __syncthreads();
#pragma unroll
        for (int i = 0; i < 4; ++i) {
            int n = tn * 32 + ly + i * 8;
            float v = tile[lx][ly + i * 8];
            __bf16 bv = (__bf16)v;
            Wt[(size_t)n * H_ + tk * 32 + lx] = *(unsigned short*)&bv;
        }
    } else {
        int blk = blockIdx.x - 256;          // 0..127
        int b = blk >> 1;
        int h = (blk & 1) * 256 + threadIdx.x;
        float acc = b1[h] + b2[h];
        const float* hp = hidden + b * H_;
        const float* wp = W2 + h;
#pragma unroll 16
        for (int k = 0; k < H_; ++k) acc = fmaf(hp[k], wp[(size_t)k * H_], acc);
        cvals[b * H_ + h] = acc;
    }
}

// ---------------------------------------------------------------------------
// Fused score+V-dot: logits[b][s] += sum_{h in ntile} V[h]*tanh((enc@W1)[b,s,h]+cvals[b,h])
// 128x128 tile, BK=32, 4 waves, mfma 16x16x32 bf16.
// Interleaved double-buffer LDS rows (128B = buf0|buf1) + 16B-chunk XOR swizzle
// chunk' = (buf*4+c) ^ (row&7)  -> conflict-free reads AND writes.
// 32 KB LDS -> 4 blocks/CU. One barrier per k-step; loads issued early (T14).
// ---------------------------------------------------------------------------
__global__ __launch_bounds__(256, 4) void score_kernel(const float* __restrict__ enc,
                                                       const unsigned short* __restrict__ Wt,
                                                       const float* __restrict__ cvals,
                                                       const float* __restrict__ Vp,
                                                       float* __restrict__ logits) {
    __shared__ __align__(16) unsigned short As[128 * 64];
    __shared__ __align__(16) unsigned short Bs[128 * 64];

    // XCD-bijective swizzle: 4096 % 8 == 0
    int orig = blockIdx.x;
    int wg   = (orig & 7) * 512 + (orig >> 3);
    int b     = wg >> 6;
    int stile = (wg >> 2) & 15;
    int ntile = wg & 3;

    int tid  = threadIdx.x;
    int wid  = tid >> 6;
    int lane = tid & 63;
    int wm = wid >> 1, wn = wid & 1;
    int rsel = lane & 15;        // fragment row within 16
    int g    = lane >> 4;        // k-chunk 0..3

    f32x4 acc[4][4];
#pragma unroll
    for (int m = 0; m < 4; ++m)
#pragma unroll
        for (int n = 0; n < 4; ++n) acc[m][n] = (f32x4){0.f, 0.f, 0.f, 0.f};

    const float*          Abase = enc + ((size_t)(b * S_ + stile * 128)) * H_;
    const unsigned short* Bbase = Wt + ((size_t)(ntile * 128)) * H_;

    int srow = tid >> 1;             // 0..127 (staging row)
    int shalf = (tid & 1);           // which 16-elem half of the 32-k row
    int c0 = shalf * 2;              // staging chunk base (16B chunks of 8 elems)

    float4 ra[4];    // 16 f32 of A
    bf16x8 rb[2];    // 16 bf16 of B

    auto swz = [&](int row, int nbc) -> int {   // element index
        return row * 64 + ((nbc ^ (row & 7)) << 3);
    };

    auto loadAB = [&](int kt) {
        const float* ap = Abase + (size_t)srow * H_ + kt * 32 + shalf * 16;
        ra[0] = *(const float4*)(ap);
        ra[1] = *(const float4*)(ap + 4);
        ra[2] = *(const float4*)(ap + 8);
        ra[3] = *(const float4*)(ap + 12);
        const unsigned short* bp = Bbase + (size_t)srow * H_ + kt * 32 + shalf * 16;
        rb[0] = *(const bf16x8*)(bp);
        rb[1] = *(const bf16x8*)(bp + 8);
    };
    auto writeAB = [&](int nb) {
        bf16x8 va[2];
        const float* f = (const float*)&ra[0];
#pragma unroll
        for (int j = 0; j < 2; ++j)
#pragma unroll
            for (int i = 0; i < 8; ++i) va[j][i] = (__bf16)f[j * 8 + i];
#pragma unroll
        for (int j = 0; j < 2; ++j) {
            int idx = swz(srow, nb * 4 + c0 + j);
            *(bf16x8*)&As[idx] = va[j];
            *(bf16x8*)&Bs[idx] = rb[j];
        }
    };
    auto compute = [&](int cb) {
        bf16x8 af[4], bfr[4];
#pragma unroll
        for (int m = 0; m < 4; ++m) {
            int row = wm * 64 + m * 16 + rsel;
            af[m] = *(const bf16x8*)&As[swz(row, cb * 4 + g)];
        }
#pragma unroll
        for (int n = 0; n < 4; ++n) {
            int row = wn * 64 + n * 16 + rsel;
            bfr[n] = *(const bf16x8*)&Bs[swz(row, cb * 4 + g)];
        }
#pragma unroll
        for (int m = 0; m < 4; ++m)
#pragma unroll
            for (int n = 0; n < 4; ++n)
                acc[m][n] = __builtin_amdgcn_mfma_f32_16x16x32_bf16(
                    af[m], bfr[n], acc[m][n], 0, 0, 0);
    };

    // prologue
    loadAB(0);
    writeAB(0);
    __syncthreads();

    for (int kt = 0; kt < 16; ++kt) {
        int cur = kt & 1;
        if (kt < 15) loadAB(kt + 1);     // issue next loads under compute
        compute(cur);
        if (kt < 15) writeAB(cur ^ 1);   // cvt + LDS write late
        __syncthreads();
    }

    // epilogue: tanh + V-dot + 16-lane row reduce + atomic partial logits
    int csel = rsel;
    float cw[4], vv[4];
#pragma unroll
    for (int n = 0; n < 4; ++n) {
        int col = ntile * 128 + wn * 64 + n * 16 + csel;
        cw[n] = cvals[b * H_ + col];
        vv[n] = Vp[col];
    }
    float part[16];
#pragma unroll
    for (int m = 0; m < 4; ++m)
#pragma unroll
        for (int r = 0; r < 4; ++r) {
            float p = 0.f;
#pragma unroll
            for (int n = 0; n < 4; ++n) {
                float s = fast_tanh(acc[m][n][r] + cw[n]);
                p = fmaf(vv[n], s, p);
            }
            part[m * 4 + r] = p;
        }
#pragma unroll
    for (int i = 0; i < 16; ++i)
#pragma unroll
        for (int off = 1; off < 16; off <<= 1)
            part[i] += __shfl_xor(part[i], off);

    if (csel == 0) {
        int gq = lane >> 4;
#pragma unroll
        for (int m = 0; m < 4; ++m)
#pragma unroll
            for (int r = 0; r < 4; ++r) {
                int row = stile * 128 + wm * 64 + m * 16 + gq * 4 + r;
                atomicAdd(&logits[b * S_ + row], part[m * 4 + r]);
            }
    }
}

// ---------------------------------------------------------------------------
// softmax over s per b
// ---------------------------------------------------------------------------
__global__ __launch_bounds__(256) void softmax_kernel(const float* __restrict__ logits,
                                                      float* __restrict__ wout) {
    int b = blockIdx.x;
    int t = threadIdx.x;
    __shared__ float red[8];
    float v[8];
#pragma unroll
    for (int i = 0; i < 8; ++i) v[i] = logits[b * S_ + t + i * 256];
    float m = v[0];
#pragma unroll
    for (int i = 1; i < 8; ++i) m = fmaxf(m, v[i]);
#pragma unroll
    for (int off = 32; off >= 1; off >>= 1) m = fmaxf(m, __shfl_xor(m, off));
    int wid = t >> 6, lane = t & 63;
    if (lane == 0) red[wid] = m;
    __syncthreads();
    m = fmaxf(fmaxf(red[0], red[1]), fmaxf(red[2], red[3]));
    float s = 0.f;
#pragma unroll
    for (int i = 0; i < 8; ++i) { v[i] = __expf(v[i] - m); s += v[i]; }
#pragma unroll
    for (int off = 32; off >= 1; off >>= 1) s += __shfl_xor(s, off);
    if (lane == 0) red[4 + wid] = s;
    __syncthreads();
    float tot = red[4] + red[5] + red[6] + red[7];
    float inv = __fdividef(1.0f, tot);
#pragma unroll
    for (int i = 0; i < 8; ++i) wout[b * S_ + t + i * 256] = v[i] * inv;
}

// ---------------------------------------------------------------------------
// context[b][h] = sum_s w[b][s] * enc[b][s][h]
// ---------------------------------------------------------------------------
__global__ __launch_bounds__(512) void context_kernel(const float* __restrict__ enc,
                                                      const float* __restrict__ w,
                                                      float* __restrict__ ctx) {
    int b  = blockIdx.x >> 4;
    int sc = blockIdx.x & 15;
    int h  = threadIdx.x;
    const float* ep = enc + ((size_t)(b * S_ + sc * 128)) * H_ + h;
    const float* wp = w + b * S_ + sc * 128;
    float acc = 0.f;
#pragma unroll 8
    for (int i = 0; i < 128; ++i) acc = fmaf(wp[i], ep[(size_t)i * H_], acc);
    atomicAdd(&ctx[b * H_ + h], acc);
}

// ---------------------------------------------------------------------------
extern "C" void kernel_launch(void* const* d_in, const int* in_sizes, int n_in,
                              void* d_out, int out_size, void* d_ws, size_t ws_size,
                              hipStream_t stream) {
    (void)in_sizes; (void)n_in; (void)out_size; (void)ws_size;
    const float* enc    = (const float*)d_in[0];
    const float* hidden = (const float*)d_in[1];
    const float* W1     = (const float*)d_in[2];
    const float* b1     = (const float*)d_in[3];
    const float* W2     = (const float*)d_in[4];
    const float* b2     = (const float*)d_in[5];
    const float* Vp     = (const float*)d_in[6];
    // d_in[7] (bV) unused: softmax is shift-invariant and logits are not an output.

    char* ws = (char*)d_ws;
    unsigned short* Wt = (unsigned short*)ws;                    // 512 KB
    float* cvals  = (float*)(ws + 524288);                       // 128 KB
    float* logits = (float*)(ws + 524288 + 131072);              // 512 KB

    float* ctx  = (float*)d_out;          // [64,512]
    float* wout = ctx + B_ * H_;          // [64,2048,1]

    hipMemsetAsync(logits, 0, (size_t)B_ * S_ * sizeof(float), stream);
    hipMemsetAsync(ctx,    0, (size_t)B_ * H_ * sizeof(float), stream);

    prep_kernel<<<384, 256, 0, stream>>>(W1, Wt, hidden, W2, b1, b2, cvals);
    score_kernel<<<4096, 256, 0, stream>>>(enc, Wt, cvals, Vp, logits);
    softmax_kernel<<<64, 256, 0, stream>>>(logits, wout);
    context_kernel<<<1024, 512, 0, stream>>>(enc, wout, ctx);
}